// Round 6
// baseline (289.714 us; speedup 1.0000x reference)
//
#include <hip/hip_runtime.h>
#include <cstdint>
#include <cstddef>

typedef unsigned short u16;
typedef __bf16 bf16x8 __attribute__((ext_vector_type(8)));
typedef float f32x4 __attribute__((ext_vector_type(4)));

// fp32 -> bf16 round-to-nearest-even (inputs finite)
__device__ inline u16 f2b(float f) {
    uint32_t u = __builtin_bit_cast(uint32_t, f);
    u += 0x7FFFu + ((u >> 16) & 1u);
    return (u16)(u >> 16);
}

// async global->LDS DMA, 16B per lane; lds dst is wave-uniform base + lane*16
__device__ inline void gl2lds16(const u16* g, u16* l) {
    __builtin_amdgcn_global_load_lds(
        (const __attribute__((address_space(1))) void*)g,
        (__attribute__((address_space(3))) void*)l, 16, 0, 0);
}

// ---- prep: x convert + zero out (bid<8192), W transposes, zero l ------------
__global__ void prep_kernel(const float* __restrict__ x, u16* __restrict__ xb,
                            const float* __restrict__ Wq,
                            const float* __restrict__ Wk,
                            const float* __restrict__ Wv,
                            u16* __restrict__ QKWT, u16* __restrict__ WvT,
                            float* __restrict__ out, float* __restrict__ l) {
    __shared__ u16 t[32][33];
    const int bid = blockIdx.x;
    if (bid < 8192) {
        size_t i = ((size_t)bid * 256 + threadIdx.x) * 4;
        float4 v = *(const float4*)(x + i);
        uint2 pack;
        pack.x = (uint32_t)f2b(v.x) | ((uint32_t)f2b(v.y) << 16);
        pack.y = (uint32_t)f2b(v.z) | ((uint32_t)f2b(v.w) << 16);
        *(uint2*)(xb + i) = pack;
        *(float4*)(out + i) = make_float4(0.f, 0.f, 0.f, 0.f);  // same extent as x
        return;
    }
    if (bid >= 11264) {   // zero l: 8 blocks x 1024 floats
        size_t i = ((size_t)(bid - 11264) * 256 + threadIdx.x) * 4;
        *(float4*)(l + i) = make_float4(0.f, 0.f, 0.f, 0.f);
        return;
    }
    const int tb = bid - 8192;          // [0, 3072)
    const int z = tb >> 10;             // weight index
    const int rem = tb & 1023;
    const int by = (rem >> 5) * 32;     // k origin
    const int bx = (rem & 31) * 32;     // n origin
    const float* W = (z == 0) ? Wq : ((z == 1) ? Wk : Wv);
    u16* dst = (z == 0) ? QKWT : ((z == 1) ? QKWT + 1024 * 1024 : WvT);
    const float scale = (z == 0) ? 0.03125f : 1.0f;  // fold 1/sqrt(1024) into Wq
    const int tx = threadIdx.x & 31, ty = threadIdx.x >> 5;  // 32x8
    #pragma unroll
    for (int r = 0; r < 32; r += 8)
        t[ty + r][tx] = f2b(W[(size_t)(by + ty + r) * 1024 + bx + tx] * scale);
    __syncthreads();
    #pragma unroll
    for (int r = 0; r < 32; r += 8)
        dst[(size_t)(bx + ty + r) * 1024 + (by + tx)] = t[tx][ty + r];
}

// ---------------- NT GEMM body: C = A (MxK) * B^T, B stored [N][K] -----------
// Software-pipelined dbuf LDS, 1 barrier/iter, DMA(k+1) issued before MFMA(k).
// (Round-3 form: no swizzle — bank conflicts measured free under latency slack;
//  swizzle pushed VGPR 84->88, dropping 6->5 waves/SIMD and regressing.)
// EPI 0: C bf16 = acc
// EPI 2: causal mask + exp -> P bf16, atomicAdd row sums into lrow
// EPI 3: C fp32 (+)= acc / lrow[row]  (atomicAdd when split)
template<int EPI>
__device__ __forceinline__ void gemm_body(
    u16* __restrict__ smem,   // 16384 u16 = 32 KB: A0 | A1 | B0 | B1
    const u16* __restrict__ A, int lda,
    const u16* __restrict__ B, int ldb,
    char* __restrict__ Cb, int ldc,
    int m0, int n0, int Kloc, float* __restrict__ lrow, bool split = false) {
    constexpr int BK = 32;
    const int tid = threadIdx.x;
    const int lane = tid & 63, wave = tid >> 6;
    const int wm = wave >> 1, wn = wave & 1;       // 2x2 wave grid, 64x64 per wave
    const int fl = lane & 15, fh = lane >> 4;

    // staging: wave covers two 16-row chunks of A and of B per issue set
    const int q0 = wave * 2;
    const int srow = lane >> 2, skoff = (lane & 3) * 8;
    const u16* ApL0 = A + (size_t)(m0 + q0 * 16 + srow) * lda + skoff;
    const u16* ApL1 = ApL0 + (size_t)16 * lda;
    const u16* BpL0 = B + (size_t)(n0 + q0 * 16 + srow) * ldb + skoff;
    const u16* BpL1 = BpL0 + (size_t)16 * ldb;

    u16* const Ab[2] = { smem, smem + 4096 };
    u16* const Bb[2] = { smem + 8192, smem + 12288 };

    auto issue = [&](int buf, int k0) {
        gl2lds16(ApL0 + k0, Ab[buf] + q0 * 512);
        gl2lds16(ApL1 + k0, Ab[buf] + q0 * 512 + 512);
        gl2lds16(BpL0 + k0, Bb[buf] + q0 * 512);
        gl2lds16(BpL1 + k0, Bb[buf] + q0 * 512 + 512);
    };

    const f32x4 vzero = {0.f, 0.f, 0.f, 0.f};
    f32x4 acc[4][4];
    #pragma unroll
    for (int i = 0; i < 4; ++i)
        #pragma unroll
        for (int j = 0; j < 4; ++j) acc[i][j] = vzero;

    issue(0, 0);
    int buf = 0;
    for (int k0 = 0; k0 < Kloc; k0 += BK, buf ^= 1) {
        __syncthreads();                       // publishes `buf` (drains its DMA)
        if (k0 + BK < Kloc) issue(buf ^ 1, k0 + BK);   // prefetch next tile
        bf16x8 af[4], bfr[4];
        #pragma unroll
        for (int t = 0; t < 4; ++t) {
            af[t]  = *(const bf16x8*)&Ab[buf][(wm * 64 + t * 16 + fl) * BK + fh * 8];
            bfr[t] = *(const bf16x8*)&Bb[buf][(wn * 64 + t * 16 + fl) * BK + fh * 8];
        }
        #pragma unroll
        for (int mt = 0; mt < 4; ++mt)
            #pragma unroll
            for (int nt = 0; nt < 4; ++nt)
                acc[mt][nt] = __builtin_amdgcn_mfma_f32_16x16x32_bf16(
                    af[mt], bfr[nt], acc[mt][nt], 0, 0, 0);
    }

    if (EPI == 0) {
        u16* Cp = (u16*)Cb;
        #pragma unroll
        for (int mt = 0; mt < 4; ++mt)
            #pragma unroll
            for (int nt = 0; nt < 4; ++nt)
                #pragma unroll
                for (int r = 0; r < 4; ++r) {
                    int row = m0 + wm * 64 + mt * 16 + fh * 4 + r;
                    int col = n0 + wn * 64 + nt * 16 + fl;
                    Cp[(size_t)row * ldc + col] = f2b(acc[mt][nt][r]);
                }
    } else if (EPI == 2) {
        u16* Cp = (u16*)Cb;
        #pragma unroll
        for (int mt = 0; mt < 4; ++mt)
            #pragma unroll
            for (int r = 0; r < 4; ++r) {
                int row = m0 + wm * 64 + mt * 16 + fh * 4 + r;
                float part = 0.f;
                #pragma unroll
                for (int nt = 0; nt < 4; ++nt) {
                    int col = n0 + wn * 64 + nt * 16 + fl;
                    float p = (col <= row) ? __expf(acc[mt][nt][r]) : 0.f;
                    part += p;
                    Cp[(size_t)row * ldc + col] = f2b(p);
                }
                #pragma unroll
                for (int off = 1; off < 16; off <<= 1)
                    part += __shfl_xor(part, off, 64);
                if (fl == 0) atomicAdd(lrow + row, part);
            }
    } else {
        float* Cp = (float*)Cb;
        #pragma unroll
        for (int mt = 0; mt < 4; ++mt)
            #pragma unroll
            for (int r = 0; r < 4; ++r) {
                int row = m0 + wm * 64 + mt * 16 + fh * 4 + r;
                float inv = 1.0f / lrow[row];
                #pragma unroll
                for (int nt = 0; nt < 4; ++nt) {
                    int col = n0 + wn * 64 + nt * 16 + fl;
                    float v = acc[mt][nt][r] * inv;
                    if (split) atomicAdd(&Cp[(size_t)row * ldc + col], v);
                    else       Cp[(size_t)row * ldc + col] = v;
                }
            }
    }
}

// ---- merged projection dispatch: QK (1024 blocks) + V^T (512 blocks) --------
__global__ __launch_bounds__(256)
void proj_kernel(const u16* __restrict__ xb, const u16* __restrict__ QKWT,
                 const u16* __restrict__ WvT, u16* __restrict__ QK,
                 u16* __restrict__ Vt) {
    __shared__ __align__(16) u16 smem[16384];
    int bid = blockIdx.x;
    if (bid < 1024) {            // QK: [8192][2048] = xb @ QKWT^T
        int jt = bid & 15, it = bid >> 4;
        gemm_body<0>(smem, xb, 1024, QKWT, 1024, (char*)QK, 2048,
                     it * 128, jt * 128, 1024, nullptr);
    } else {                     // V^T: [1024][8192] = WvT @ xb^T
        int b = bid - 1024;
        int jt = b & 63, it = b >> 6;
        gemm_body<0>(smem, WvT, 1024, xb, 1024, (char*)Vt, 8192,
                     it * 128, jt * 128, 1024, nullptr);
    }
}

// ---- scores: compact triangular grid, P = exp(masked QK^T), row sums --------
__global__ __launch_bounds__(256)
void scores_kernel(const u16* __restrict__ QK, u16* __restrict__ P,
                   float* __restrict__ l) {
    __shared__ __align__(16) u16 smem[16384];
    const int t = blockIdx.x, z = blockIdx.y;
    int it = (int)((sqrtf(8.0f * t + 1.0f) - 1.0f) * 0.5f);
    while ((it + 1) * (it + 2) / 2 <= t) ++it;
    while (it * (it + 1) / 2 > t) --it;
    const int jt = t - it * (it + 1) / 2;
    const u16* Qz = QK + (size_t)z * 2048 * 2048;  // Q cols [0,1024)
    const u16* Kz = Qz + 1024;                     // K cols [1024,2048)
    u16* Pz = P + (size_t)z * 2048 * 2048;
    gemm_body<2>(smem, Qz, 2048, Kz, 2048, (char*)Pz, 2048,
                 it * 128, jt * 128, 1024, l + (size_t)z * 2048);
}

// ---- output: O = (P/l) @ V; K split into <=512 chunks, heavy-first ----------
// per (z,it): nc = ceil((it+1)/4) chunks; grid y in [0,40) enumerates (it,c)
// heavy-first; x = jt + 8*z mixes z so heavy chunks of all z dispatch first.
__global__ __launch_bounds__(256)
void out_kernel(const u16* __restrict__ P, const u16* __restrict__ Vt,
                float* __restrict__ out, float* __restrict__ l) {
    __shared__ __align__(16) u16 smem[16384];
    const int jt = blockIdx.x & 7, z = blockIdx.x >> 3;
    int c = blockIdx.y, it = 15;
    for (int i = 15; i >= 0; --i) {
        int n = (i >> 2) + 1;
        if (c < n) { it = i; break; }
        c -= n;
    }
    const int Ktot = (it + 1) * 128;
    const int k0 = c * 512;
    const int kloc = min(512, Ktot - k0);
    const bool split = (Ktot > 512);
    gemm_body<3>(smem, P + (size_t)z * 2048 * 2048 + k0, 2048,
                 Vt + (size_t)z * 2048 + k0, 8192,
                 (char*)(out + (size_t)z * 2048 * 1024), 1024,
                 it * 128, jt * 128, kloc, l + (size_t)z * 2048, split);
}

extern "C" void kernel_launch(void* const* d_in, const int* in_sizes, int n_in,
                              void* d_out, int out_size, void* d_ws, size_t ws_size,
                              hipStream_t stream) {
    (void)in_sizes; (void)n_in; (void)out_size; (void)ws_size;
    const float* x  = (const float*)d_in[0];
    const float* Wq = (const float*)d_in[1];
    const float* Wk = (const float*)d_in[2];
    const float* Wv = (const float*)d_in[3];
    float* out = (float*)d_out;

    const size_t MB = 1u << 20;
    char* ws = (char*)d_ws;
    u16* xb   = (u16*)(ws);              // [8192][1024] bf16       16 MB
    u16* QKWT = (u16*)(ws + 16 * MB);    // [2048][1024] (WqT*s | WkT) 4 MB
    u16* WvT  = (u16*)(ws + 20 * MB);    // [1024][1024]             2 MB
    u16* QK   = (u16*)(ws + 22 * MB);    // [8192][2048] (Q|K)      32 MB
    u16* Vt   = (u16*)(ws + 54 * MB);    // V^T [1024][8192]        16 MB
    u16* P    = (u16*)(ws + 70 * MB);    // exp(S) [4][2048][2048]  32 MB
    float* l  = (float*)(ws + 102 * MB); // row sums [4][2048]      32 KB

    prep_kernel<<<8192 + 3072 + 8, 256, 0, stream>>>(x, xb, Wq, Wk, Wv, QKWT, WvT, out, l);
    proj_kernel<<<1536, 256, 0, stream>>>(xb, QKWT, WvT, QK, Vt);
    scores_kernel<<<dim3(136, 4), 256, 0, stream>>>(QK, P, l);
    out_kernel<<<dim3(32, 40), 256, 0, stream>>>(P, Vt, out, l);
}

// Round 7
// 258.009 us; speedup vs baseline: 1.1229x; 1.1229x over previous
//
#include <hip/hip_runtime.h>
#include <cstdint>
#include <cstddef>

typedef unsigned short u16;
typedef __bf16 bf16x8 __attribute__((ext_vector_type(8)));
typedef float f32x4 __attribute__((ext_vector_type(4)));

// fp32 -> bf16 round-to-nearest-even (inputs finite)
__device__ inline u16 f2b(float f) {
    uint32_t u = __builtin_bit_cast(uint32_t, f);
    u += 0x7FFFu + ((u >> 16) & 1u);
    return (u16)(u >> 16);
}

// async global->LDS DMA, 16B per lane; lds dst is wave-uniform base + lane*16
__device__ inline void gl2lds16(const u16* g, u16* l) {
    __builtin_amdgcn_global_load_lds(
        (const __attribute__((address_space(1))) void*)g,
        (__attribute__((address_space(3))) void*)l, 16, 0, 0);
}

// ---- prep: x convert (bid<8192), W transposes, zero l -----------------------
__global__ void prep_kernel(const float* __restrict__ x, u16* __restrict__ xb,
                            const float* __restrict__ Wq,
                            const float* __restrict__ Wk,
                            const float* __restrict__ Wv,
                            u16* __restrict__ QKWT, u16* __restrict__ WvT,
                            float* __restrict__ l) {
    __shared__ u16 t[32][33];
    const int bid = blockIdx.x;
    if (bid < 8192) {
        size_t i = ((size_t)bid * 256 + threadIdx.x) * 4;
        float4 v = *(const float4*)(x + i);
        uint2 pack;
        pack.x = (uint32_t)f2b(v.x) | ((uint32_t)f2b(v.y) << 16);
        pack.y = (uint32_t)f2b(v.z) | ((uint32_t)f2b(v.w) << 16);
        *(uint2*)(xb + i) = pack;
        return;
    }
    if (bid >= 11264) {   // zero l: 8 blocks x 1024 floats
        size_t i = ((size_t)(bid - 11264) * 256 + threadIdx.x) * 4;
        *(float4*)(l + i) = make_float4(0.f, 0.f, 0.f, 0.f);
        return;
    }
    const int tb = bid - 8192;          // [0, 3072)
    const int z = tb >> 10;             // weight index
    const int rem = tb & 1023;
    const int by = (rem >> 5) * 32;     // k origin
    const int bx = (rem & 31) * 32;     // n origin
    const float* W = (z == 0) ? Wq : ((z == 1) ? Wk : Wv);
    u16* dst = (z == 0) ? QKWT : ((z == 1) ? QKWT + 1024 * 1024 : WvT);
    const float scale = (z == 0) ? 0.03125f : 1.0f;  // fold 1/sqrt(1024) into Wq
    const int tx = threadIdx.x & 31, ty = threadIdx.x >> 5;  // 32x8
    #pragma unroll
    for (int r = 0; r < 32; r += 8)
        t[ty + r][tx] = f2b(W[(size_t)(by + ty + r) * 1024 + bx + tx] * scale);
    __syncthreads();
    #pragma unroll
    for (int r = 0; r < 32; r += 8)
        dst[(size_t)(bx + ty + r) * 1024 + (by + tx)] = t[tx][ty + r];
}

// ---------------- NT GEMM body: C = A (MxK) * B^T, B stored [N][K] -----------
// Software-pipelined dbuf LDS, 1 barrier/iter, DMA(k+1) issued before MFMA(k).
// (No LDS swizzle: conflicts measured hidden under latency slack; swizzle's
//  VGPR cost regressed occupancy in R5. No atomic K-split: RMW traffic
//  regressed R6.)
// EPI 0: C bf16 = acc
// EPI 2: causal mask + exp -> P bf16, atomicAdd row sums into lrow
// EPI 3: C fp32 = acc / lrow[row]
template<int EPI>
__device__ __forceinline__ void gemm_body(
    u16* __restrict__ smem,   // 16384 u16 = 32 KB: A0 | A1 | B0 | B1
    const u16* __restrict__ A, int lda,
    const u16* __restrict__ B, int ldb,
    char* __restrict__ Cb, int ldc,
    int m0, int n0, int Kloc, float* __restrict__ lrow) {
    constexpr int BK = 32;
    const int tid = threadIdx.x;
    const int lane = tid & 63, wave = tid >> 6;
    const int wm = wave >> 1, wn = wave & 1;       // 2x2 wave grid, 64x64 per wave
    const int fl = lane & 15, fh = lane >> 4;

    // staging: wave covers two 16-row chunks of A and of B per issue set
    const int q0 = wave * 2;
    const int srow = lane >> 2, skoff = (lane & 3) * 8;
    const u16* ApL0 = A + (size_t)(m0 + q0 * 16 + srow) * lda + skoff;
    const u16* ApL1 = ApL0 + (size_t)16 * lda;
    const u16* BpL0 = B + (size_t)(n0 + q0 * 16 + srow) * ldb + skoff;
    const u16* BpL1 = BpL0 + (size_t)16 * ldb;

    u16* const Ab[2] = { smem, smem + 4096 };
    u16* const Bb[2] = { smem + 8192, smem + 12288 };

    auto issue = [&](int buf, int k0) {
        gl2lds16(ApL0 + k0, Ab[buf] + q0 * 512);
        gl2lds16(ApL1 + k0, Ab[buf] + q0 * 512 + 512);
        gl2lds16(BpL0 + k0, Bb[buf] + q0 * 512);
        gl2lds16(BpL1 + k0, Bb[buf] + q0 * 512 + 512);
    };

    const f32x4 vzero = {0.f, 0.f, 0.f, 0.f};
    f32x4 acc[4][4];
    #pragma unroll
    for (int i = 0; i < 4; ++i)
        #pragma unroll
        for (int j = 0; j < 4; ++j) acc[i][j] = vzero;

    issue(0, 0);
    int buf = 0;
    for (int k0 = 0; k0 < Kloc; k0 += BK, buf ^= 1) {
        __syncthreads();                       // publishes `buf` (drains its DMA)
        if (k0 + BK < Kloc) issue(buf ^ 1, k0 + BK);   // prefetch next tile
        bf16x8 af[4], bfr[4];
        #pragma unroll
        for (int t = 0; t < 4; ++t) {
            af[t]  = *(const bf16x8*)&Ab[buf][(wm * 64 + t * 16 + fl) * BK + fh * 8];
            bfr[t] = *(const bf16x8*)&Bb[buf][(wn * 64 + t * 16 + fl) * BK + fh * 8];
        }
        #pragma unroll
        for (int mt = 0; mt < 4; ++mt)
            #pragma unroll
            for (int nt = 0; nt < 4; ++nt)
                acc[mt][nt] = __builtin_amdgcn_mfma_f32_16x16x32_bf16(
                    af[mt], bfr[nt], acc[mt][nt], 0, 0, 0);
    }

    if (EPI == 0) {
        u16* Cp = (u16*)Cb;
        #pragma unroll
        for (int mt = 0; mt < 4; ++mt)
            #pragma unroll
            for (int nt = 0; nt < 4; ++nt)
                #pragma unroll
                for (int r = 0; r < 4; ++r) {
                    int row = m0 + wm * 64 + mt * 16 + fh * 4 + r;
                    int col = n0 + wn * 64 + nt * 16 + fl;
                    Cp[(size_t)row * ldc + col] = f2b(acc[mt][nt][r]);
                }
    } else if (EPI == 2) {
        u16* Cp = (u16*)Cb;
        #pragma unroll
        for (int mt = 0; mt < 4; ++mt)
            #pragma unroll
            for (int r = 0; r < 4; ++r) {
                int row = m0 + wm * 64 + mt * 16 + fh * 4 + r;
                float part = 0.f;
                #pragma unroll
                for (int nt = 0; nt < 4; ++nt) {
                    int col = n0 + wn * 64 + nt * 16 + fl;
                    float p = (col <= row) ? __expf(acc[mt][nt][r]) : 0.f;
                    part += p;
                    Cp[(size_t)row * ldc + col] = f2b(p);
                }
                #pragma unroll
                for (int off = 1; off < 16; off <<= 1)
                    part += __shfl_xor(part, off, 64);
                if (fl == 0) atomicAdd(lrow + row, part);
            }
    } else {
        float* Cp = (float*)Cb;
        #pragma unroll
        for (int mt = 0; mt < 4; ++mt)
            #pragma unroll
            for (int r = 0; r < 4; ++r) {
                int row = m0 + wm * 64 + mt * 16 + fh * 4 + r;
                float inv = 1.0f / lrow[row];
                #pragma unroll
                for (int nt = 0; nt < 4; ++nt) {
                    int col = n0 + wn * 64 + nt * 16 + fl;
                    Cp[(size_t)row * ldc + col] = acc[mt][nt][r] * inv;
                }
            }
    }
}

// ---- pass 1a: QK projection only (1024 blocks) ------------------------------
__global__ __launch_bounds__(256)
void projqk_kernel(const u16* __restrict__ xb, const u16* __restrict__ QKWT,
                   u16* __restrict__ QK) {
    __shared__ __align__(16) u16 smem[16384];
    const int jt = blockIdx.x & 15, it = blockIdx.x >> 4;
    gemm_body<0>(smem, xb, 1024, QKWT, 1024, (char*)QK, 2048,
                 it * 128, jt * 128, 1024, nullptr);
}

// ---- pass 2: scores (544 blocks) + independent V^T projection (512 blocks) --
// Both depend only on prep/projQK outputs; merged so V^T blocks fill CUs
// alongside the triangular scores grid.
__global__ __launch_bounds__(256)
void mid_kernel(const u16* __restrict__ QK, u16* __restrict__ P,
                float* __restrict__ l,
                const u16* __restrict__ WvT, const u16* __restrict__ xb,
                u16* __restrict__ Vt) {
    __shared__ __align__(16) u16 smem[16384];
    const int bid = blockIdx.x;
    if (bid < 544) {             // scores: compact triangular grid, 4 z
        const int z = bid / 136, t = bid - z * 136;
        int it = (int)((sqrtf(8.0f * t + 1.0f) - 1.0f) * 0.5f);
        while ((it + 1) * (it + 2) / 2 <= t) ++it;
        while (it * (it + 1) / 2 > t) --it;
        const int jt = t - it * (it + 1) / 2;
        const u16* Qz = QK + (size_t)z * 2048 * 2048;  // Q cols [0,1024)
        const u16* Kz = Qz + 1024;                     // K cols [1024,2048)
        u16* Pz = P + (size_t)z * 2048 * 2048;
        gemm_body<2>(smem, Qz, 2048, Kz, 2048, (char*)Pz, 2048,
                     it * 128, jt * 128, 1024, l + (size_t)z * 2048);
    } else {                     // V^T: [1024][8192] = WvT @ xb^T
        const int b = bid - 544;
        const int jt = b & 63, it = b >> 6;
        gemm_body<0>(smem, WvT, 1024, xb, 1024, (char*)Vt, 8192,
                     it * 128, jt * 128, 1024, nullptr);
    }
}

// ---- pass 3: O = (P/l) @ V; heavy row-tiles first, no split, plain stores ---
// grid (32,16): x packs (jt,z) so all 32 heaviest tiles dispatch first;
// y = 15-it puts long-K blocks at the front of the dispatch order.
__global__ __launch_bounds__(256)
void out_kernel(const u16* __restrict__ P, const u16* __restrict__ Vt,
                float* __restrict__ out, float* __restrict__ l) {
    __shared__ __align__(16) u16 smem[16384];
    const int jt = blockIdx.x & 7, z = blockIdx.x >> 3;
    const int it = 15 - (int)blockIdx.y;
    gemm_body<3>(smem, P + (size_t)z * 2048 * 2048, 2048,
                 Vt + (size_t)z * 2048, 8192,
                 (char*)(out + (size_t)z * 2048 * 1024), 1024,
                 it * 128, jt * 128, (it + 1) * 128, l + (size_t)z * 2048);
}

extern "C" void kernel_launch(void* const* d_in, const int* in_sizes, int n_in,
                              void* d_out, int out_size, void* d_ws, size_t ws_size,
                              hipStream_t stream) {
    (void)in_sizes; (void)n_in; (void)out_size; (void)ws_size;
    const float* x  = (const float*)d_in[0];
    const float* Wq = (const float*)d_in[1];
    const float* Wk = (const float*)d_in[2];
    const float* Wv = (const float*)d_in[3];
    float* out = (float*)d_out;

    const size_t MB = 1u << 20;
    char* ws = (char*)d_ws;
    u16* xb   = (u16*)(ws);              // [8192][1024] bf16       16 MB
    u16* QKWT = (u16*)(ws + 16 * MB);    // [2048][1024] (WqT*s | WkT) 4 MB
    u16* WvT  = (u16*)(ws + 20 * MB);    // [1024][1024]             2 MB
    u16* QK   = (u16*)(ws + 22 * MB);    // [8192][2048] (Q|K)      32 MB
    u16* Vt   = (u16*)(ws + 54 * MB);    // V^T [1024][8192]        16 MB
    u16* P    = (u16*)(ws + 70 * MB);    // exp(S) [4][2048][2048]  32 MB
    float* l  = (float*)(ws + 102 * MB); // row sums [4][2048]      32 KB

    prep_kernel<<<8192 + 3072 + 8, 256, 0, stream>>>(x, xb, Wq, Wk, Wv, QKWT, WvT, l);
    projqk_kernel<<<1024, 256, 0, stream>>>(xb, QKWT, QK);
    mid_kernel<<<1056, 256, 0, stream>>>(QK, P, l, WvT, xb, Vt);
    out_kernel<<<dim3(32, 16), 256, 0, stream>>>(P, Vt, out, l);
}